// Round 22
// baseline (252.388 us; speedup 1.0000x reference)
//
#include <hip/hip_runtime.h>
#include <cstdint>
#include <cstddef>
#include <math.h>

#define NT 512
#define TROWS 64
#define HS 68   // ht column stride (floats)

typedef __attribute__((ext_vector_type(8))) short bf16x8;
typedef __attribute__((ext_vector_type(4))) float f32x4;

#define WSP2_OFF 614400   // u16 offsets in d_ws
#define WSP3_OFF 712704
#define WSP4_OFF 737280

__device__ __forceinline__ uint32_t f2u(float f) {
  uint32_t b = __float_as_uint(f);
  return (b & 0x80000000u) ? ~b : (b | 0x80000000u);
}

__device__ __forceinline__ unsigned short f2bf(float f) {  // RNE f32->bf16
  uint32_t u = __float_as_uint(f);
  return (unsigned short)((u + 0x7FFFu + ((u >> 16) & 1u)) >> 16);
}
__device__ __forceinline__ float bf2f(unsigned short h) {
  return __uint_as_float(((uint32_t)h) << 16);
}

// async global->LDS 16B/lane: lds dest = wave-uniform base + lane*16
__device__ __forceinline__ void gload_lds16(const void* g, void* l) {
  __builtin_amdgcn_global_load_lds(
      (const __attribute__((address_space(1))) unsigned int*)g,
      (__attribute__((address_space(3))) unsigned int*)l, 16, 0, 0);
}

// prep: split w1 (256x784) into 3 bf16 planes, k padded to 800 with zeros.
// Lane-linear: per chunk c, plane p, tile t (16 cols):
// u16[(((c*3+p)*16)+t)*512 + (kg*16+col16)*8 + k8] — MFMA lane l reads
// offset l*8, so every B-fragment read is a wave-contiguous 1 KB sweep.
__global__ void prep_w1_kernel(const float* __restrict__ w1,
                               unsigned short* __restrict__ wsp) {
  const int idx = blockIdx.x * 256 + threadIdx.x;
  if (idx >= 256 * 800) return;
  const int col = idx / 800, k = idx % 800;
  const float v = (k < 784) ? w1[col * 784 + k] : 0.0f;
  const unsigned short h = f2bf(v);
  const float r1 = v - bf2f(h);
  const unsigned short m = f2bf(r1);
  const float r2 = r1 - bf2f(m);
  const unsigned short l = f2bf(r2);
  const int c = k >> 5, kin = k & 31, kg = kin >> 3, k8 = kin & 7;
  const int tile = col >> 4, c16 = col & 15;
  const size_t base =
      ((size_t)(c * 3) * 16 + tile) * 512 + (size_t)(kg * 16 + c16) * 8 + k8;
  wsp[base]            = h;
  wsp[base + 16 * 512] = m;
  wsp[base + 32 * 512] = l;
}

// prep2: w2 (128x256) -> 3 planes at WSP2_OFF.
__global__ void prep_w2_kernel(const float* __restrict__ w2,
                               unsigned short* __restrict__ wsp) {
  const int idx = blockIdx.x * 256 + threadIdx.x;
  if (idx >= 128 * 256) return;
  const int col = idx / 256, k = idx % 256;
  const float v = w2[col * 256 + k];
  const unsigned short h = f2bf(v);
  const float r1 = v - bf2f(h);
  const unsigned short m = f2bf(r1);
  const float r2 = r1 - bf2f(m);
  const unsigned short l = f2bf(r2);
  const int c2 = k >> 5, kin = k & 31, kg = kin >> 3, k8 = kin & 7;
  const int tile = col >> 4, c16 = col & 15;
  unsigned short* w2p = wsp + WSP2_OFF;
  const size_t base =
      ((size_t)(c2 * 3) * 8 + tile) * 512 + (size_t)(kg * 16 + c16) * 8 + k8;
  w2p[base]            = h;
  w2p[base + 8 * 512]  = m;
  w2p[base + 16 * 512] = l;
}

// prep3: w3 (64x128) -> 3 planes at WSP3_OFF.
__global__ void prep_w3_kernel(const float* __restrict__ w3,
                               unsigned short* __restrict__ wsp) {
  const int idx = blockIdx.x * 256 + threadIdx.x;
  if (idx >= 64 * 128) return;
  const int col = idx / 128, k = idx % 128;
  const float v = w3[col * 128 + k];
  const unsigned short h = f2bf(v);
  const float r1 = v - bf2f(h);
  const unsigned short m = f2bf(r1);
  const float r2 = r1 - bf2f(m);
  const unsigned short l = f2bf(r2);
  const int c3 = k >> 5, kin = k & 31, kg = kin >> 3, k8 = kin & 7;
  const int tile = col >> 4, c16 = col & 15;
  unsigned short* w3p = wsp + WSP3_OFF;
  const size_t base =
      ((size_t)(c3 * 3) * 4 + tile) * 512 + (size_t)(kg * 16 + c16) * 8 + k8;
  w3p[base]            = h;
  w3p[base + 4 * 512]  = m;
  w3p[base + 8 * 512]  = l;
}

// prep4: w4 (32x64) -> 3 planes at WSP4_OFF.
__global__ void prep_w4_kernel(const float* __restrict__ w4,
                               unsigned short* __restrict__ wsp) {
  const int idx = blockIdx.x * 256 + threadIdx.x;
  if (idx >= 32 * 64) return;
  const int col = idx / 64, k = idx % 64;
  const float v = w4[col * 64 + k];
  const unsigned short h = f2bf(v);
  const float r1 = v - bf2f(h);
  const unsigned short m = f2bf(r1);
  const float r2 = r1 - bf2f(m);
  const unsigned short l = f2bf(r2);
  const int c4 = k >> 5, kin = k & 31, kg = kin >> 3, k8 = kin & 7;
  const int tile = col >> 4, c16 = col & 15;
  unsigned short* w4p = wsp + WSP4_OFF;
  const size_t base =
      ((size_t)(c4 * 3) * 2 + tile) * 512 + (size_t)(kg * 16 + c16) * 8 + k8;
  w4p[base]            = h;
  w4p[base + 2 * 512]  = m;
  w4p[base + 4 * 512]  = l;
}

// Exact k-th largest per row (binary search in sortable-u32 space) with
// EXACT early exit: if cnt(u>=cand)==K at any bit, {u>=cand} IS the
// winner set, so stop. Ties fall through to the full search.
template<int NCOL, int K>
__device__ __forceinline__ void kwinners_inplace(
    float* __restrict__ ht, const float* __restrict__ duty,
    float pct, int wid, int lane)
{
  constexpr int Q = (NCOL + 63) / 64;
  const bool active = (NCOL >= 64) || (lane < NCOL);
  float Bq[Q];
#pragma unroll
  for (int q = 0; q < Q; ++q) {
    const int col = active ? (lane + 64 * q) : 0;
    const float arg = 1.4f * (pct - duty[col]);
    Bq[q] = (float)exp((double)arg);
  }
#pragma unroll
  for (int g = 0; g < 2; ++g) {
    const int r0 = wid * 8 + g * 4;
    float h[Q][4];
    uint32_t u[Q][4];
#pragma unroll
    for (int q = 0; q < Q; ++q) {
      const int col = active ? (lane + 64 * q) : 0;
      *(float4*)&h[q][0] = *(const float4*)&ht[col * HS + r0];
#pragma unroll
      for (int m = 0; m < 4; ++m)
        u[q][m] = active ? f2u(h[q][m] * Bq[q]) : 0u;
    }
    uint32_t prefix[4] = {0u, 0u, 0u, 0u};
    int done = 0;                 // wave-uniform per-row done flags
    for (int bit = 31; bit >= 0 && done != 15; --bit) {
#pragma unroll
      for (int m = 0; m < 4; ++m) {
        if (done & (1 << m)) continue;     // uniform branch
        const uint32_t cand = prefix[m] | (1u << bit);
        int cnt = 0;
#pragma unroll
        for (int q = 0; q < Q; ++q)
          cnt += __popcll(__ballot(u[q][m] >= cand));
        if (cnt >= K) {
          prefix[m] = cand;
          if (cnt == K) done |= (1 << m);  // exact winner set found
        }
      }
    }
#pragma unroll
    for (int m = 0; m < 4; ++m)
#pragma unroll
      for (int q = 0; q < Q; ++q)
        h[q][m] = (u[q][m] >= prefix[m]) ? h[q][m] : 0.0f;
#pragma unroll
    for (int q = 0; q < Q; ++q) {
      const int col = lane + 64 * q;
      if (active) *(float4*)&ht[col * HS + r0] = *(const float4*)&h[q][0];
    }
  }
}

// in-register truncation 3-way bf16 split of 8 floats
#define SPLIT3(a8, Ah, Am, Al)                                   \
  _Pragma("unroll")                                              \
  for (int j = 0; j < 8; ++j) {                                  \
    const uint32_t u0 = __float_as_uint(a8[j]);                  \
    Ah[j] = (short)(u0 >> 16);                                   \
    const float r1 = a8[j] - __uint_as_float(u0 & 0xFFFF0000u);  \
    const uint32_t u1 = __float_as_uint(r1);                     \
    Am[j] = (short)(u1 >> 16);                                   \
    const float r2 = r1 - __uint_as_float(u1 & 0xFFFF0000u);     \
    Al[j] = (short)(__float_as_uint(r2) >> 16);                  \
  }

#define MFMA6(ACC, Ah, Am, Al, PB, PSTRIDE)                                  \
  {                                                                          \
    bf16x8 B_ = *(const bf16x8*)(PB);                                        \
    ACC = __builtin_amdgcn_mfma_f32_16x16x32_bf16(Ah, B_, ACC, 0, 0, 0);     \
    ACC = __builtin_amdgcn_mfma_f32_16x16x32_bf16(Am, B_, ACC, 0, 0, 0);     \
    ACC = __builtin_amdgcn_mfma_f32_16x16x32_bf16(Al, B_, ACC, 0, 0, 0);     \
    B_ = *(const bf16x8*)((PB) + (PSTRIDE));                                 \
    ACC = __builtin_amdgcn_mfma_f32_16x16x32_bf16(Ah, B_, ACC, 0, 0, 0);     \
    ACC = __builtin_amdgcn_mfma_f32_16x16x32_bf16(Am, B_, ACC, 0, 0, 0);     \
    B_ = *(const bf16x8*)((PB) + 2 * (PSTRIDE));                             \
    ACC = __builtin_amdgcn_mfma_f32_16x16x32_bf16(Ah, B_, ACC, 0, 0, 0);     \
  }

// (NT,4): pin 4 waves/EU (16/CU, the LDS-capped max) -> 64-VGPR budget.
__global__ __launch_bounds__(NT, 4)
void sparse_fcnet_kernel(
    const float* __restrict__ x,
    const unsigned short* __restrict__ wsp,   // pre-split w1..w4 planes
    const float* __restrict__ b1, const float* __restrict__ b2,
    const float* __restrict__ b3, const float* __restrict__ b4,
    const float* __restrict__ w5, const float* __restrict__ b5,
    const float* __restrict__ duty1, const float* __restrict__ duty2,
    const float* __restrict__ duty3, const float* __restrict__ duty4,
    float* __restrict__ out)
{
  __shared__ float ht[256 * HS];   // 69632 B; wp dbuf alias in L1 (65536 B)
  __shared__ float stg[2592];      // 10368 B  (total 80000 B -> 2 blocks/CU)

  const int tid  = threadIdx.x;
  const int lane = tid & 63;
  const int wid  = tid >> 6;       // 0..7
  const int R0   = blockIdx.x * TROWS;

  const int rt  = wid & 3;         // row tile: rows rt*16..+15
  const int ch  = wid >> 2;        // col half
  const int l15 = lane & 15;
  const int kg  = lane >> 4;       // 0..3

  // ---- Layer 1 via bf16x3 split MFMA: h1[64][256] = x @ w1.T + b1
  // Double-buffered async staging of Bh+Bm planes (one barrier per chunk;
  // next chunk's global_load_lds in flight across this chunk's MFMAs).
  // Bl plane read direct from L2-hot wsp with one-tile-ahead prefetch.
  {
    unsigned short* wp = (unsigned short*)ht;  // 2 bufs x 16384 u16 = 65536 B

    f32x4 acc[8];
#pragma unroll
    for (int t = 0; t < 8; ++t) acc[t] = 0.0f;

    const size_t xrow = (size_t)(R0 + rt * 16 + l15) * 784;
    float xc[8];
    {   // chunk 0 x prefetch (k = kg*8 .. +7, always < 784)
      const float4 va = *(const float4*)&x[xrow + kg * 8];
      const float4 vb = *(const float4*)&x[xrow + kg * 8 + 4];
      xc[0]=va.x; xc[1]=va.y; xc[2]=va.z; xc[3]=va.w;
      xc[4]=vb.x; xc[5]=vb.y; xc[6]=vb.z; xc[7]=vb.w;
    }

    // prologue: stage chunk 0 (Bh+Bm = first 16384 u16 of the chunk) -> buf0
    {
      const unsigned short* wc = wsp;
#pragma unroll
      for (int u = 0; u < 4; ++u) {
        const int ubase = (u * 512 + wid * 64) * 8;
        gload_lds16(wc + ubase + lane * 8, &wp[ubase]);
      }
    }
    __syncthreads();                      // drain chunk-0 staging

    for (int c = 0; c < 25; ++c) {
      unsigned short* cur = wp + (c & 1) * 16384;
      unsigned short* nxt = wp + ((c + 1) & 1) * 16384;
      if (c < 24) {                       // issue next chunk's Bh+Bm NOW
        const unsigned short* wc = wsp + (size_t)(c + 1) * 24576;
#pragma unroll
        for (int u = 0; u < 4; ++u) {
          const int ubase = (u * 512 + wid * 64) * 8;
          gload_lds16(wc + ubase + lane * 8, &nxt[ubase]);
        }
      }
      bf16x8 Ah, Am, Al;
      SPLIT3(xc, Ah, Am, Al)
      if (c < 24) {                       // prefetch next chunk's x
        const int kn = (c + 1) * 32 + kg * 8;
        if (kn < 784) {
          const float4 va = *(const float4*)&x[xrow + kn];
          const float4 vb = *(const float4*)&x[xrow + kn + 4];
          xc[0]=va.x; xc[1]=va.y; xc[2]=va.z; xc[3]=va.w;
          xc[4]=vb.x; xc[5]=vb.y; xc[6]=vb.z; xc[7]=vb.w;
        } else {
#pragma unroll
          for (int j = 0; j < 8; ++j) xc[j] = 0.0f;
        }
      }

      // Bl plane base for this wave's col-half, this chunk (global, L2-hot)
      const unsigned short* wl =
          wsp + (size_t)c * 24576 + 16384 + (size_t)(ch * 8) * 512 + lane * 8;
      bf16x8 Bl = *(const bf16x8*)(wl);   // tile 0

#pragma unroll
      for (int t = 0; t < 8; ++t) {
        bf16x8 Bln;
        if (t < 7) Bln = *(const bf16x8*)(wl + (t + 1) * 512);
        const unsigned short* pb = cur + (ch * 8 + t) * 512 + lane * 8;
        bf16x8 B_ = *(const bf16x8*)(pb);                  // Bh (LDS)
        acc[t] = __builtin_amdgcn_mfma_f32_16x16x32_bf16(Ah, B_, acc[t], 0, 0, 0);
        acc[t] = __builtin_amdgcn_mfma_f32_16x16x32_bf16(Am, B_, acc[t], 0, 0, 0);
        acc[t] = __builtin_amdgcn_mfma_f32_16x16x32_bf16(Al, B_, acc[t], 0, 0, 0);
        B_ = *(const bf16x8*)(pb + 8192);                  // Bm (LDS)
        acc[t] = __builtin_amdgcn_mfma_f32_16x16x32_bf16(Ah, B_, acc[t], 0, 0, 0);
        acc[t] = __builtin_amdgcn_mfma_f32_16x16x32_bf16(Am, B_, acc[t], 0, 0, 0);
        acc[t] = __builtin_amdgcn_mfma_f32_16x16x32_bf16(Ah, Bl, acc[t], 0, 0, 0);
        if (t < 7) Bl = Bln;
      }
      __syncthreads();   // cur reads done + nxt staging drained (vmcnt 0)
    }

    // epilogue: C-layout col=lane&15, row=(lane>>4)*4+reg  -> ht[col][row]
#pragma unroll
    for (int t = 0; t < 8; ++t) {
      const int col_g = ch * 128 + t * 16 + l15;
      const float bv = b1[col_g];
      float4 v = {acc[t].x + bv, acc[t].y + bv, acc[t].z + bv, acc[t].w + bv};
      *(float4*)&ht[col_g * HS + rt * 16 + kg * 4] = v;
    }
  }
  __syncthreads();
  kwinners_inplace<256, 128>(ht, duty1, 0.5f, wid, lane);
  __syncthreads();

  // ---- Layer 2 via bf16x3 split MFMA: h2[64][128] = h1m @ w2.T + b2
  {
    const unsigned short* wsp2 = wsp + WSP2_OFF;
    f32x4 acc2[4];
#pragma unroll
    for (int t = 0; t < 4; ++t) acc2[t] = 0.0f;

    for (int c2 = 0; c2 < 8; ++c2) {
      float a8[8];
#pragma unroll
      for (int j = 0; j < 8; ++j)
        a8[j] = ht[(c2 * 32 + kg * 8 + j) * HS + rt * 16 + l15];
      bf16x8 Ah, Am, Al;
      SPLIT3(a8, Ah, Am, Al)
      const unsigned short* wc2 =
          wsp2 + (size_t)(c2 * 3) * 4096 + (size_t)(ch * 4) * 512 + lane * 8;
#pragma unroll
      for (int t = 0; t < 4; ++t) {
        const unsigned short* pb = wc2 + t * 512;
        MFMA6(acc2[t], Ah, Am, Al, pb, 4096)
      }
    }
    __syncthreads();   // all h1m reads done before h2 overwrites ht
#pragma unroll
    for (int t = 0; t < 4; ++t) {
      const int col_g = ch * 64 + t * 16 + l15;
      const float bv = b2[col_g];
      float4 v = {acc2[t].x + bv, acc2[t].y + bv, acc2[t].z + bv, acc2[t].w + bv};
      *(float4*)&ht[col_g * HS + rt * 16 + kg * 4] = v;
    }
  }
  __syncthreads();
  kwinners_inplace<128, 13>(ht, duty2, 0.1f, wid, lane);
  __syncthreads();

  // ---- Layer 3 via bf16x3 split MFMA: h3[64][64] = h2m @ w3.T + b3
  {
    const unsigned short* wsp3 = wsp + WSP3_OFF;
    f32x4 acc3[2];
    acc3[0] = 0.0f; acc3[1] = 0.0f;

    for (int c3 = 0; c3 < 4; ++c3) {
      float a8[8];
#pragma unroll
      for (int j = 0; j < 8; ++j)
        a8[j] = ht[(c3 * 32 + kg * 8 + j) * HS + rt * 16 + l15];
      bf16x8 Ah, Am, Al;
      SPLIT3(a8, Ah, Am, Al)
      const unsigned short* wc3 =
          wsp3 + (size_t)(c3 * 3) * 2048 + (size_t)(ch * 2) * 512 + lane * 8;
#pragma unroll
      for (int t = 0; t < 2; ++t) {
        const unsigned short* pb = wc3 + t * 512;
        MFMA6(acc3[t], Ah, Am, Al, pb, 2048)
      }
    }
    __syncthreads();   // all h2m reads done before h3 overwrites ht
#pragma unroll
    for (int t = 0; t < 2; ++t) {
      const int col_g = ch * 32 + t * 16 + l15;
      const float bv = b3[col_g];
      float4 v = {acc3[t].x + bv, acc3[t].y + bv, acc3[t].z + bv, acc3[t].w + bv};
      *(float4*)&ht[col_g * HS + rt * 16 + kg * 4] = v;
    }
  }
  __syncthreads();
  kwinners_inplace<64, 32>(ht, duty3, 0.5f, wid, lane);
  __syncthreads();

  // ---- Layer 4 via bf16x3 split MFMA: h4[64][32] = h3m @ w4.T + b4
  {
    const unsigned short* wsp4 = wsp + WSP4_OFF;
    f32x4 acc4;
    acc4 = 0.0f;

    for (int c4 = 0; c4 < 2; ++c4) {
      float a8[8];
#pragma unroll
      for (int j = 0; j < 8; ++j)
        a8[j] = ht[(c4 * 32 + kg * 8 + j) * HS + rt * 16 + l15];
      bf16x8 Ah, Am, Al;
      SPLIT3(a8, Ah, Am, Al)
      const unsigned short* pb =
          wsp4 + (size_t)(c4 * 3) * 1024 + (size_t)ch * 512 + lane * 8;
      MFMA6(acc4, Ah, Am, Al, pb, 1024)
    }
    __syncthreads();   // all h3m reads done before h4 overwrites ht
    {
      const int col_g = ch * 16 + l15;
      const float bv = b4[col_g];
      float4 v = {acc4.x + bv, acc4.y + bv, acc4.z + bv, acc4.w + bv};
      *(float4*)&ht[col_g * HS + rt * 16 + kg * 4] = v;
    }
  }
  __syncthreads();
  kwinners_inplace<32, 16>(ht, duty4, 0.5f, wid, lane);
  __syncthreads();

  // ---- Layer 5: out[64][10] = h4m[64][32] @ w5.T + b5
  {
    if (tid < 320) stg[tid] = w5[tid];
    if (tid < 10)  stg[320 + tid] = b5[tid];
    __syncthreads();
    for (int o = tid; o < 640; o += NT) {
      const int row = o / 10, col = o % 10;
      float acc = 0.0f;
#pragma unroll
      for (int kk = 0; kk < 32; ++kk)
        acc = fmaf(ht[kk * HS + row], stg[col * 32 + kk], acc);
      out[(size_t)(R0 + row) * 10 + col] = acc + stg[320 + col];
    }
  }
}

extern "C" void kernel_launch(void* const* d_in, const int* in_sizes, int n_in,
                              void* d_out, int out_size, void* d_ws, size_t ws_size,
                              hipStream_t stream) {
  const float* x     = (const float*)d_in[0];
  const float* w1    = (const float*)d_in[1];
  const float* b1    = (const float*)d_in[2];
  const float* w2    = (const float*)d_in[3];
  const float* b2    = (const float*)d_in[4];
  const float* w3    = (const float*)d_in[5];
  const float* b3    = (const float*)d_in[6];
  const float* w4    = (const float*)d_in[7];
  const float* b4    = (const float*)d_in[8];
  const float* w5    = (const float*)d_in[9];
  const float* b5    = (const float*)d_in[10];
  const float* duty1 = (const float*)d_in[11];
  const float* duty2 = (const float*)d_in[12];
  const float* duty3 = (const float*)d_in[13];
  const float* duty4 = (const float*)d_in[14];
  float* out = (float*)d_out;
  unsigned short* wsp = (unsigned short*)d_ws;   // ~1.48 MB of planes

  hipLaunchKernelGGL(prep_w1_kernel, dim3(800), dim3(256), 0, stream, w1, wsp);
  hipLaunchKernelGGL(prep_w2_kernel, dim3(128), dim3(256), 0, stream, w2, wsp);
  hipLaunchKernelGGL(prep_w3_kernel, dim3(32),  dim3(256), 0, stream, w3, wsp);
  hipLaunchKernelGGL(prep_w4_kernel, dim3(8),   dim3(256), 0, stream, w4, wsp);

  const int rows = in_sizes[0] / 784;
  const int grid = rows / TROWS;
  hipLaunchKernelGGL(sparse_fcnet_kernel, dim3(grid), dim3(NT), 0, stream,
                     x, wsp, b1, b2, b3, b4, w5, b5,
                     duty1, duty2, duty3, duty4, out);
}

// Round 23
// 221.254 us; speedup vs baseline: 1.1407x; 1.1407x over previous
//
#include <hip/hip_runtime.h>
#include <cstdint>
#include <cstddef>
#include <math.h>

#define NT 512
#define TROWS 64
#define HS 68   // ht column stride (floats)

typedef __attribute__((ext_vector_type(8))) short bf16x8;
typedef __attribute__((ext_vector_type(4))) float f32x4;

#define WSP2_OFF 614400   // u16 offsets in d_ws
#define WSP3_OFF 712704
#define WSP4_OFF 737280

__device__ __forceinline__ uint32_t f2u(float f) {
  uint32_t b = __float_as_uint(f);
  return (b & 0x80000000u) ? ~b : (b | 0x80000000u);
}

__device__ __forceinline__ unsigned short f2bf(float f) {  // RNE f32->bf16
  uint32_t u = __float_as_uint(f);
  return (unsigned short)((u + 0x7FFFu + ((u >> 16) & 1u)) >> 16);
}
__device__ __forceinline__ float bf2f(unsigned short h) {
  return __uint_as_float(((uint32_t)h) << 16);
}

// async global->LDS 16B/lane: lds dest = wave-uniform base + lane*16
__device__ __forceinline__ void gload_lds16(const void* g, void* l) {
  __builtin_amdgcn_global_load_lds(
      (const __attribute__((address_space(1))) unsigned int*)g,
      (__attribute__((address_space(3))) unsigned int*)l, 16, 0, 0);
}

// Merged prep: split w1..w4 into 3 bf16 planes each (lane-linear layout).
// Blocks [0,800): w1 | [800,928): w2 | [928,960): w3 | [960,968): w4.
// Layout per matrix (chunk c of 32 k, plane p, tile t of 16 cols):
//   u16[((c*3+p)*NT16 + t)*512 + (kg*16 + col16)*8 + k8]
// so MFMA lane l reads offset l*8 (wave-contiguous 1 KB per fragment).
__global__ void prep_all_kernel(
    const float* __restrict__ w1, const float* __restrict__ w2,
    const float* __restrict__ w3, const float* __restrict__ w4,
    unsigned short* __restrict__ wsp) {
  const int b = blockIdx.x, t = threadIdx.x;
  if (b < 800) {                      // ---- w1: 256x784, k padded to 800
    const int idx = b * 256 + t;
    const int col = idx / 800, k = idx % 800;
    const float v = (k < 784) ? w1[col * 784 + k] : 0.0f;
    const unsigned short h = f2bf(v);
    const float r1 = v - bf2f(h);
    const unsigned short m = f2bf(r1);
    const float r2 = r1 - bf2f(m);
    const unsigned short l = f2bf(r2);
    const int c = k >> 5, kin = k & 31, kg = kin >> 3, k8 = kin & 7;
    const int tile = col >> 4, c16 = col & 15;
    const size_t base =
        ((size_t)(c * 3) * 16 + tile) * 512 + (size_t)(kg * 16 + c16) * 8 + k8;
    wsp[base]            = h;
    wsp[base + 16 * 512] = m;
    wsp[base + 32 * 512] = l;
  } else if (b < 928) {               // ---- w2: 128x256
    const int idx = (b - 800) * 256 + t;
    const int col = idx / 256, k = idx % 256;
    const float v = w2[col * 256 + k];
    const unsigned short h = f2bf(v);
    const float r1 = v - bf2f(h);
    const unsigned short m = f2bf(r1);
    const float r2 = r1 - bf2f(m);
    const unsigned short l = f2bf(r2);
    const int c2 = k >> 5, kin = k & 31, kg = kin >> 3, k8 = kin & 7;
    const int tile = col >> 4, c16 = col & 15;
    unsigned short* w2p = wsp + WSP2_OFF;
    const size_t base =
        ((size_t)(c2 * 3) * 8 + tile) * 512 + (size_t)(kg * 16 + c16) * 8 + k8;
    w2p[base]            = h;
    w2p[base + 8 * 512]  = m;
    w2p[base + 16 * 512] = l;
  } else if (b < 960) {               // ---- w3: 64x128
    const int idx = (b - 928) * 256 + t;
    const int col = idx / 128, k = idx % 128;
    const float v = w3[col * 128 + k];
    const unsigned short h = f2bf(v);
    const float r1 = v - bf2f(h);
    const unsigned short m = f2bf(r1);
    const float r2 = r1 - bf2f(m);
    const unsigned short l = f2bf(r2);
    const int c3 = k >> 5, kin = k & 31, kg = kin >> 3, k8 = kin & 7;
    const int tile = col >> 4, c16 = col & 15;
    unsigned short* w3p = wsp + WSP3_OFF;
    const size_t base =
        ((size_t)(c3 * 3) * 4 + tile) * 512 + (size_t)(kg * 16 + c16) * 8 + k8;
    w3p[base]            = h;
    w3p[base + 4 * 512]  = m;
    w3p[base + 8 * 512]  = l;
  } else {                            // ---- w4: 32x64
    const int idx = (b - 960) * 256 + t;
    const int col = idx / 64, k = idx % 64;
    const float v = w4[col * 64 + k];
    const unsigned short h = f2bf(v);
    const float r1 = v - bf2f(h);
    const unsigned short m = f2bf(r1);
    const float r2 = r1 - bf2f(m);
    const unsigned short l = f2bf(r2);
    const int c4 = k >> 5, kin = k & 31, kg = kin >> 3, k8 = kin & 7;
    const int tile = col >> 4, c16 = col & 15;
    unsigned short* w4p = wsp + WSP4_OFF;
    const size_t base =
        ((size_t)(c4 * 3) * 2 + tile) * 512 + (size_t)(kg * 16 + c16) * 8 + k8;
    w4p[base]            = h;
    w4p[base + 2 * 512]  = m;
    w4p[base + 4 * 512]  = l;
  }
}

// Exact k-th largest per row (binary search in sortable-u32 space) with
// EXACT early exit: if cnt(u>=cand)==K at any bit, {u>=cand} IS the
// winner set, so stop. Ties fall through to the full search.
template<int NCOL, int K>
__device__ __forceinline__ void kwinners_inplace(
    float* __restrict__ ht, const float* __restrict__ duty,
    float pct, int wid, int lane)
{
  constexpr int Q = (NCOL + 63) / 64;
  const bool active = (NCOL >= 64) || (lane < NCOL);
  float Bq[Q];
#pragma unroll
  for (int q = 0; q < Q; ++q) {
    const int col = active ? (lane + 64 * q) : 0;
    const float arg = 1.4f * (pct - duty[col]);
    Bq[q] = (float)exp((double)arg);
  }
#pragma unroll
  for (int g = 0; g < 2; ++g) {
    const int r0 = wid * 8 + g * 4;
    float h[Q][4];
    uint32_t u[Q][4];
#pragma unroll
    for (int q = 0; q < Q; ++q) {
      const int col = active ? (lane + 64 * q) : 0;
      *(float4*)&h[q][0] = *(const float4*)&ht[col * HS + r0];
#pragma unroll
      for (int m = 0; m < 4; ++m)
        u[q][m] = active ? f2u(h[q][m] * Bq[q]) : 0u;
    }
    uint32_t prefix[4] = {0u, 0u, 0u, 0u};
    int done = 0;                 // wave-uniform per-row done flags
    for (int bit = 31; bit >= 0 && done != 15; --bit) {
#pragma unroll
      for (int m = 0; m < 4; ++m) {
        if (done & (1 << m)) continue;     // uniform branch
        const uint32_t cand = prefix[m] | (1u << bit);
        int cnt = 0;
#pragma unroll
        for (int q = 0; q < Q; ++q)
          cnt += __popcll(__ballot(u[q][m] >= cand));
        if (cnt >= K) {
          prefix[m] = cand;
          if (cnt == K) done |= (1 << m);  // exact winner set found
        }
      }
    }
#pragma unroll
    for (int m = 0; m < 4; ++m)
#pragma unroll
      for (int q = 0; q < Q; ++q)
        h[q][m] = (u[q][m] >= prefix[m]) ? h[q][m] : 0.0f;
#pragma unroll
    for (int q = 0; q < Q; ++q) {
      const int col = lane + 64 * q;
      if (active) *(float4*)&ht[col * HS + r0] = *(const float4*)&h[q][0];
    }
  }
}

// in-register truncation 3-way bf16 split of 8 floats
#define SPLIT3(a8, Ah, Am, Al)                                   \
  _Pragma("unroll")                                              \
  for (int j = 0; j < 8; ++j) {                                  \
    const uint32_t u0 = __float_as_uint(a8[j]);                  \
    Ah[j] = (short)(u0 >> 16);                                   \
    const float r1 = a8[j] - __uint_as_float(u0 & 0xFFFF0000u);  \
    const uint32_t u1 = __float_as_uint(r1);                     \
    Am[j] = (short)(u1 >> 16);                                   \
    const float r2 = r1 - __uint_as_float(u1 & 0xFFFF0000u);     \
    Al[j] = (short)(__float_as_uint(r2) >> 16);                  \
  }

#define MFMA6(ACC, Ah, Am, Al, PB, PSTRIDE)                                  \
  {                                                                          \
    bf16x8 B_ = *(const bf16x8*)(PB);                                        \
    ACC = __builtin_amdgcn_mfma_f32_16x16x32_bf16(Ah, B_, ACC, 0, 0, 0);     \
    ACC = __builtin_amdgcn_mfma_f32_16x16x32_bf16(Am, B_, ACC, 0, 0, 0);     \
    ACC = __builtin_amdgcn_mfma_f32_16x16x32_bf16(Al, B_, ACC, 0, 0, 0);     \
    B_ = *(const bf16x8*)((PB) + (PSTRIDE));                                 \
    ACC = __builtin_amdgcn_mfma_f32_16x16x32_bf16(Ah, B_, ACC, 0, 0, 0);     \
    ACC = __builtin_amdgcn_mfma_f32_16x16x32_bf16(Am, B_, ACC, 0, 0, 0);     \
    B_ = *(const bf16x8*)((PB) + 2 * (PSTRIDE));                             \
    ACC = __builtin_amdgcn_mfma_f32_16x16x32_bf16(Ah, B_, ACC, 0, 0, 0);     \
  }

// (NT,4): pin 4 waves/EU (16/CU, the LDS-capped max) -> 64-VGPR budget.
__global__ __launch_bounds__(NT, 4)
void sparse_fcnet_kernel(
    const float* __restrict__ x,
    const unsigned short* __restrict__ wsp,   // pre-split w1..w4 planes
    const float* __restrict__ b1, const float* __restrict__ b2,
    const float* __restrict__ b3, const float* __restrict__ b4,
    const float* __restrict__ w5, const float* __restrict__ b5,
    const float* __restrict__ duty1, const float* __restrict__ duty2,
    const float* __restrict__ duty3, const float* __restrict__ duty4,
    float* __restrict__ out)
{
  __shared__ float ht[256 * HS];   // 69632 B; wp alias during L1 (49152 B)
  __shared__ float stg[2592];      // 10368 B  (total 80000 B -> 2 blocks/CU)

  const int tid  = threadIdx.x;
  const int lane = tid & 63;
  const int wid  = tid >> 6;       // 0..7
  const int R0   = blockIdx.x * TROWS;

  const int rt  = wid & 3;         // row tile: rows rt*16..+15
  const int ch  = wid >> 2;        // col half
  const int l15 = lane & 15;
  const int kg  = lane >> 4;       // 0..3

  // ---- Layer 1 via bf16x3 split MFMA: h1[64][256] = x @ w1.T + b1
  // LDS-staged B via async global_load_lds (no VGPR round-trip).
  {
    unsigned short* wp = (unsigned short*)ht;  // [3][16][512] u16 = 49152 B

    f32x4 acc[8];
#pragma unroll
    for (int t = 0; t < 8; ++t) acc[t] = 0.0f;

    const size_t xrow = (size_t)(R0 + rt * 16 + l15) * 784;
    float xc[8];
    {   // chunk 0 x prefetch (k = kg*8 .. +7, always < 784)
      const float4 va = *(const float4*)&x[xrow + kg * 8];
      const float4 vb = *(const float4*)&x[xrow + kg * 8 + 4];
      xc[0]=va.x; xc[1]=va.y; xc[2]=va.z; xc[3]=va.w;
      xc[4]=vb.x; xc[5]=vb.y; xc[6]=vb.z; xc[7]=vb.w;
    }

    for (int c = 0; c < 25; ++c) {
      __syncthreads();                    // prev chunk's B-reads done
      {   // async staging: 6 units/wave of 64 lanes x 16 B, contiguous
        const unsigned short* wc = wsp + (size_t)c * 24576;
#pragma unroll
        for (int u = 0; u < 6; ++u) {
          const int ubase = (u * 512 + wid * 64) * 8;
          gload_lds16(wc + ubase + lane * 8, &wp[ubase]);
        }
      }
      bf16x8 Ah, Am, Al;
      SPLIT3(xc, Ah, Am, Al)
      if (c < 24) {                       // prefetch next chunk's x
        const int kn = (c + 1) * 32 + kg * 8;
        if (kn < 784) {
          const float4 va = *(const float4*)&x[xrow + kn];
          const float4 vb = *(const float4*)&x[xrow + kn + 4];
          xc[0]=va.x; xc[1]=va.y; xc[2]=va.z; xc[3]=va.w;
          xc[4]=vb.x; xc[5]=vb.y; xc[6]=vb.z; xc[7]=vb.w;
        } else {
#pragma unroll
          for (int j = 0; j < 8; ++j) xc[j] = 0.0f;
        }
      }
      __syncthreads();                    // vmcnt(0) drain: staging visible

#pragma unroll
      for (int t = 0; t < 8; ++t) {
        const unsigned short* pb = (const unsigned short*)&wp[(ch * 8 + t) * 512 + lane * 8];
        MFMA6(acc[t], Ah, Am, Al, pb, 8192)
      }
    }
    __syncthreads();   // all wp reads done before ht f32 writes overlap it

    // epilogue: C-layout col=lane&15, row=(lane>>4)*4+reg  -> ht[col][row]
#pragma unroll
    for (int t = 0; t < 8; ++t) {
      const int col_g = ch * 128 + t * 16 + l15;
      const float bv = b1[col_g];
      float4 v = {acc[t].x + bv, acc[t].y + bv, acc[t].z + bv, acc[t].w + bv};
      *(float4*)&ht[col_g * HS + rt * 16 + kg * 4] = v;
    }
  }
  __syncthreads();
  kwinners_inplace<256, 128>(ht, duty1, 0.5f, wid, lane);
  __syncthreads();

  // ---- Layer 2 via bf16x3 split MFMA: h2[64][128] = h1m @ w2.T + b2
  {
    const unsigned short* wsp2 = wsp + WSP2_OFF;
    f32x4 acc2[4];
#pragma unroll
    for (int t = 0; t < 4; ++t) acc2[t] = 0.0f;

    for (int c2 = 0; c2 < 8; ++c2) {
      float a8[8];
#pragma unroll
      for (int j = 0; j < 8; ++j)
        a8[j] = ht[(c2 * 32 + kg * 8 + j) * HS + rt * 16 + l15];
      bf16x8 Ah, Am, Al;
      SPLIT3(a8, Ah, Am, Al)
      const unsigned short* wc2 =
          wsp2 + (size_t)(c2 * 3) * 4096 + (size_t)(ch * 4) * 512 + lane * 8;
#pragma unroll
      for (int t = 0; t < 4; ++t) {
        const unsigned short* pb = wc2 + t * 512;
        MFMA6(acc2[t], Ah, Am, Al, pb, 4096)
      }
    }
    __syncthreads();   // all h1m reads done before h2 overwrites ht
#pragma unroll
    for (int t = 0; t < 4; ++t) {
      const int col_g = ch * 64 + t * 16 + l15;
      const float bv = b2[col_g];
      float4 v = {acc2[t].x + bv, acc2[t].y + bv, acc2[t].z + bv, acc2[t].w + bv};
      *(float4*)&ht[col_g * HS + rt * 16 + kg * 4] = v;
    }
  }
  __syncthreads();
  kwinners_inplace<128, 13>(ht, duty2, 0.1f, wid, lane);
  __syncthreads();

  // ---- Layer 3 via bf16x3 split MFMA: h3[64][64] = h2m @ w3.T + b3
  {
    const unsigned short* wsp3 = wsp + WSP3_OFF;
    f32x4 acc3[2];
    acc3[0] = 0.0f; acc3[1] = 0.0f;

    for (int c3 = 0; c3 < 4; ++c3) {
      float a8[8];
#pragma unroll
      for (int j = 0; j < 8; ++j)
        a8[j] = ht[(c3 * 32 + kg * 8 + j) * HS + rt * 16 + l15];
      bf16x8 Ah, Am, Al;
      SPLIT3(a8, Ah, Am, Al)
      const unsigned short* wc3 =
          wsp3 + (size_t)(c3 * 3) * 2048 + (size_t)(ch * 2) * 512 + lane * 8;
#pragma unroll
      for (int t = 0; t < 2; ++t) {
        const unsigned short* pb = wc3 + t * 512;
        MFMA6(acc3[t], Ah, Am, Al, pb, 2048)
      }
    }
    __syncthreads();   // all h2m reads done before h3 overwrites ht
#pragma unroll
    for (int t = 0; t < 2; ++t) {
      const int col_g = ch * 32 + t * 16 + l15;
      const float bv = b3[col_g];
      float4 v = {acc3[t].x + bv, acc3[t].y + bv, acc3[t].z + bv, acc3[t].w + bv};
      *(float4*)&ht[col_g * HS + rt * 16 + kg * 4] = v;
    }
  }
  __syncthreads();
  kwinners_inplace<64, 32>(ht, duty3, 0.5f, wid, lane);
  __syncthreads();

  // ---- Layer 4 via bf16x3 split MFMA: h4[64][32] = h3m @ w4.T + b4
  {
    const unsigned short* wsp4 = wsp + WSP4_OFF;
    f32x4 acc4;
    acc4 = 0.0f;

    for (int c4 = 0; c4 < 2; ++c4) {
      float a8[8];
#pragma unroll
      for (int j = 0; j < 8; ++j)
        a8[j] = ht[(c4 * 32 + kg * 8 + j) * HS + rt * 16 + l15];
      bf16x8 Ah, Am, Al;
      SPLIT3(a8, Ah, Am, Al)
      const unsigned short* pb =
          wsp4 + (size_t)(c4 * 3) * 1024 + (size_t)ch * 512 + lane * 8;
      MFMA6(acc4, Ah, Am, Al, pb, 1024)
    }
    __syncthreads();   // all h3m reads done before h4 overwrites ht
    {
      const int col_g = ch * 16 + l15;
      const float bv = b4[col_g];
      float4 v = {acc4.x + bv, acc4.y + bv, acc4.z + bv, acc4.w + bv};
      *(float4*)&ht[col_g * HS + rt * 16 + kg * 4] = v;
    }
  }
  __syncthreads();
  kwinners_inplace<32, 16>(ht, duty4, 0.5f, wid, lane);
  __syncthreads();

  // ---- Layer 5: out[64][10] = h4m[64][32] @ w5.T + b5
  {
    if (tid < 320) stg[tid] = w5[tid];
    if (tid < 10)  stg[320 + tid] = b5[tid];
    __syncthreads();
    for (int o = tid; o < 640; o += NT) {
      const int row = o / 10, col = o % 10;
      float acc = 0.0f;
#pragma unroll
      for (int kk = 0; kk < 32; ++kk)
        acc = fmaf(ht[kk * HS + row], stg[col * 32 + kk], acc);
      out[(size_t)(R0 + row) * 10 + col] = acc + stg[320 + col];
    }
  }
}

extern "C" void kernel_launch(void* const* d_in, const int* in_sizes, int n_in,
                              void* d_out, int out_size, void* d_ws, size_t ws_size,
                              hipStream_t stream) {
  const float* x     = (const float*)d_in[0];
  const float* w1    = (const float*)d_in[1];
  const float* b1    = (const float*)d_in[2];
  const float* w2    = (const float*)d_in[3];
  const float* b2    = (const float*)d_in[4];
  const float* w3    = (const float*)d_in[5];
  const float* b3    = (const float*)d_in[6];
  const float* w4    = (const float*)d_in[7];
  const float* b4    = (const float*)d_in[8];
  const float* w5    = (const float*)d_in[9];
  const float* b5    = (const float*)d_in[10];
  const float* duty1 = (const float*)d_in[11];
  const float* duty2 = (const float*)d_in[12];
  const float* duty3 = (const float*)d_in[13];
  const float* duty4 = (const float*)d_in[14];
  float* out = (float*)d_out;
  unsigned short* wsp = (unsigned short*)d_ws;   // ~1.48 MB of planes

  hipLaunchKernelGGL(prep_all_kernel, dim3(968), dim3(256), 0, stream,
                     w1, w2, w3, w4, wsp);

  const int rows = in_sizes[0] / 784;
  const int grid = rows / TROWS;
  hipLaunchKernelGGL(sparse_fcnet_kernel, dim3(grid), dim3(NT), 0, stream,
                     x, wsp, b1, b2, b3, b4, w5, b5,
                     duty1, duty2, duty3, duty4, out);
}